// Round 8
// baseline (2907.064 us; speedup 1.0000x reference)
//
#include <hip/hip_runtime.h>
#include <hip/hip_bf16.h>

// Problem constants (F is hard-coded 31 in the reference / TAG)
#define FDIM 31
#define FPAD 32      // padded row length in elements
#define RSTRIDE 16   // row stride in uints (32 bf16 = 64 B = 16 uints = 1 cache line)

// Coarse bucketing for CSR build: 2048 nodes per bucket
#define CBITS 11
#define CW    (1 << CBITS)
#define MAXBUK 256
#define TILE 4096

// ---- bf16 pack/unpack helpers (packed as 2 bf16 per uint, little-endian)
__device__ __forceinline__ float bf_lo(unsigned u) { return __uint_as_float(u << 16); }
__device__ __forceinline__ float bf_hi(unsigned u) { return __uint_as_float(u & 0xFFFF0000u); }
__device__ __forceinline__ unsigned pack2(float lo, float hi) {
    unsigned a = __float_as_uint(lo), b = __float_as_uint(hi);
    unsigned ra = (a + 0x7FFFu + ((a >> 16) & 1u)) >> 16;   // RNE
    unsigned rb = (b + 0x7FFFu + ((b >> 16) & 1u)) >> 16;
    return ra | (rb << 16);
}

// first index in sorted gid[0..Ntot) with gid[idx] >= g
__device__ __forceinline__ int lb_gid(const int* __restrict__ gid, int Ntot, int g) {
    int lo = 0, hi = Ntot;
    while (lo < hi) { int mid = (lo + hi) >> 1; if (gid[mid] < g) lo = mid + 1; else hi = mid; }
    return lo;
}

// --------------------------------------------------- multisplit (level 1)
__global__ __launch_bounds__(256) void multisplit_kernel(
    const int* __restrict__ src, const int* __restrict__ dst,
    int* __restrict__ gcnt, int* __restrict__ bucketed,
    int cap, int E, int nbuk)
{
    __shared__ int ordered[TILE];
    __shared__ int hist[MAXBUK];
    __shared__ int lofs[MAXBUK + 1];
    __shared__ int base_[MAXBUK];
    __shared__ int cur[MAXBUK];
    const int tid = threadIdx.x;
    const int e0 = blockIdx.x * TILE;
    const int n = min(TILE, E - e0);
    if (tid < MAXBUK) hist[tid] = 0;
    __syncthreads();
    for (int i = tid; i < n; i += 256)
        atomicAdd(&hist[dst[e0 + i] >> CBITS], 1);
    __syncthreads();
    if (tid == 0) {
        int a = 0;
        for (int b = 0; b < nbuk; ++b) { lofs[b] = a; a += hist[b]; }
        lofs[nbuk] = a;
    }
    __syncthreads();
    if (tid < nbuk) {
        int h = hist[tid];
        base_[tid] = h ? atomicAdd(&gcnt[tid], h) : 0;
        cur[tid] = lofs[tid];
    }
    __syncthreads();
    for (int i = tid; i < n; i += 256) {
        int s = src[e0 + i], d = dst[e0 + i];
        int b = d >> CBITS;
        int r = atomicAdd(&cur[b], 1);
        ordered[r] = (s << CBITS) | (d & (CW - 1));
    }
    __syncthreads();
    for (int i = tid; i < n; i += 256) {
        int lo = 0, hi = nbuk;
        while (hi - lo > 1) {
            int mid = (lo + hi) >> 1;
            if (lofs[mid] <= i) lo = mid; else hi = mid;
        }
        int b = lo;
        int pos = base_[b] + (i - lofs[b]);
        if (pos < cap) bucketed[(size_t)b * cap + pos] = ordered[i];
    }
}

// --------------------------------------------------- per-bucket degree
__global__ __launch_bounds__(1024) void bucket_deg_kernel(
    const int* __restrict__ bucketed, const int* __restrict__ gcnt,
    int* __restrict__ deg, int cap, int N)
{
    __shared__ int hist[CW];
    const int b = blockIdx.x, tid = threadIdx.x;
    for (int t = tid; t < CW; t += 1024) hist[t] = 0;
    __syncthreads();
    const int cnt = min(gcnt[b], cap);
    const int* reg = bucketed + (size_t)b * cap;
    for (int i = tid; i < cnt; i += 1024)
        atomicAdd(&hist[reg[i] & (CW - 1)], 1);
    __syncthreads();
    const int base_node = b << CBITS;
    for (int t = tid; t < CW; t += 1024) {
        int node = base_node + t;
        if (node < N) deg[node] = hist[t];
    }
}

// --------------------------------------------------- per-bucket CSR fill
__global__ __launch_bounds__(1024) void bucket_fill_kernel(
    const int* __restrict__ bucketed, const int* __restrict__ gcnt,
    const int* __restrict__ rowptr, int* __restrict__ col, int cap, int N)
{
    __shared__ int lcur[CW];
    const int b = blockIdx.x, tid = threadIdx.x;
    const int base_node = b << CBITS;
    for (int t = tid; t < CW; t += 1024) {
        int node = base_node + t;
        lcur[t] = (node < N) ? rowptr[node] : 0;
    }
    __syncthreads();
    const int cnt = min(gcnt[b], cap);
    const int* reg = bucketed + (size_t)b * cap;
    for (int i = tid; i < cnt; i += 1024) {
        int e = reg[i];
        int p = atomicAdd(&lcur[e & (CW - 1)], 1);
        col[p] = e >> CBITS;
    }
}

// --------------------------------------------------- scans

__global__ void scan_block_kernel(const int* __restrict__ deg, int* __restrict__ out,
                                  int* __restrict__ partials, int N) {
    __shared__ int s[256];
    int i = blockIdx.x * 256 + threadIdx.x;
    int v = (i < N) ? deg[i] : 0;
    s[threadIdx.x] = v;
    __syncthreads();
    for (int off = 1; off < 256; off <<= 1) {
        int t = (threadIdx.x >= off) ? s[threadIdx.x - off] : 0;
        __syncthreads();
        s[threadIdx.x] += t;
        __syncthreads();
    }
    if (i < N) out[i] = s[threadIdx.x] - v;
    if (threadIdx.x == 255) partials[blockIdx.x] = s[255];
}

__global__ void scan_partials_kernel(int* __restrict__ partials, int nb) {
    __shared__ int s[256];
    __shared__ int carry;
    if (threadIdx.x == 0) carry = 0;
    __syncthreads();
    for (int base = 0; base < nb; base += 256) {
        int i = base + threadIdx.x;
        int v = (i < nb) ? partials[i] : 0;
        s[threadIdx.x] = v;
        __syncthreads();
        for (int off = 1; off < 256; off <<= 1) {
            int t = (threadIdx.x >= off) ? s[threadIdx.x - off] : 0;
            __syncthreads();
            s[threadIdx.x] += t;
            __syncthreads();
        }
        int res = carry + s[threadIdx.x] - v;
        int tot = s[255];
        __syncthreads();
        if (i < nb) partials[i] = res;
        if (threadIdx.x == 0) carry += tot;
        __syncthreads();
    }
}

__global__ void finalize_kernel(int* __restrict__ rowptr, const int* __restrict__ partials,
                                const int* __restrict__ deg,
                                float* __restrict__ normv, int N, int E) {
    int i = blockIdx.x * 256 + threadIdx.x;
    if (i >= N) return;
    int r = rowptr[i] + partials[i >> 8];
    rowptr[i] = r;
    int d = deg[i];
    normv[i] = rsqrtf((float)(d > 0 ? d : 1));
    if (i == 0) rowptr[N] = E;
}

// ---- fp32 x -> packed bf16 padded rows (one thread per packed uint)
__global__ void cast_x_kernel(const float* __restrict__ x, unsigned* __restrict__ A, int N) {
    int idx = blockIdx.x * 256 + threadIdx.x;
    if (idx >= N * RSTRIDE) return;
    int n = idx >> 4, q = idx & 15;
    int f0 = 2 * q, f1 = 2 * q + 1;
    float lo = (f0 < FDIM) ? x[(size_t)n * FDIM + f0] : 0.0f;
    float hi = (f1 < FDIM) ? x[(size_t)n * FDIM + f1] : 0.0f;
    A[idx] = pack2(lo, hi);
}

// ---- shared gather body: accumulate norm-scaled neighbor rows into acc[8]
#define GATHER_EDGE(cN, nN, vN)                                                        \
    acc0 = fmaf(nN, bf_lo(vN.x), acc0); acc1 = fmaf(nN, bf_hi(vN.x), acc1);            \
    acc2 = fmaf(nN, bf_lo(vN.y), acc2); acc3 = fmaf(nN, bf_hi(vN.y), acc3);            \
    acc4 = fmaf(nN, bf_lo(vN.z), acc4); acc5 = fmaf(nN, bf_hi(vN.z), acc5);            \
    acc6 = fmaf(nN, bf_lo(vN.w), acc6); acc7 = fmaf(nN, bf_hi(vN.w), acc7);

// ------------------------------------------------------------------ SpMM hop (hop 1)
__global__ __launch_bounds__(256) void spmm_kernel(const unsigned* __restrict__ Hin,
                                                   unsigned* __restrict__ Hout,
                                                   const int* __restrict__ rowptr,
                                                   const int* __restrict__ col,
                                                   const float* __restrict__ normv, int N) {
    int node = blockIdx.x * 64 + (threadIdx.x >> 2);
    int sub = threadIdx.x & 3;
    if (node >= N) return;
    int s = rowptr[node], e = rowptr[node + 1];
    float acc0 = 0.f, acc1 = 0.f, acc2 = 0.f, acc3 = 0.f;
    float acc4 = 0.f, acc5 = 0.f, acc6 = 0.f, acc7 = 0.f;
    int k = s;
    for (; k + 8 <= e; k += 8) {
        int c0 = col[k + 0], c1 = col[k + 1], c2 = col[k + 2], c3 = col[k + 3];
        int c4 = col[k + 4], c5 = col[k + 5], c6 = col[k + 6], c7 = col[k + 7];
        uint4 v0 = *((const uint4*)(Hin + (size_t)c0 * RSTRIDE) + sub);
        uint4 v1 = *((const uint4*)(Hin + (size_t)c1 * RSTRIDE) + sub);
        uint4 v2 = *((const uint4*)(Hin + (size_t)c2 * RSTRIDE) + sub);
        uint4 v3 = *((const uint4*)(Hin + (size_t)c3 * RSTRIDE) + sub);
        uint4 v4 = *((const uint4*)(Hin + (size_t)c4 * RSTRIDE) + sub);
        uint4 v5 = *((const uint4*)(Hin + (size_t)c5 * RSTRIDE) + sub);
        uint4 v6 = *((const uint4*)(Hin + (size_t)c6 * RSTRIDE) + sub);
        uint4 v7 = *((const uint4*)(Hin + (size_t)c7 * RSTRIDE) + sub);
        float n0 = normv[c0], n1 = normv[c1], n2 = normv[c2], n3 = normv[c3];
        float n4 = normv[c4], n5 = normv[c5], n6 = normv[c6], n7 = normv[c7];
        GATHER_EDGE(c0, n0, v0) GATHER_EDGE(c1, n1, v1)
        GATHER_EDGE(c2, n2, v2) GATHER_EDGE(c3, n3, v3)
        GATHER_EDGE(c4, n4, v4) GATHER_EDGE(c5, n5, v5)
        GATHER_EDGE(c6, n6, v6) GATHER_EDGE(c7, n7, v7)
    }
    for (; k < e; ++k) {
        int c = col[k];
        float ns = normv[c];
        uint4 v = *((const uint4*)(Hin + (size_t)c * RSTRIDE) + sub);
        GATHER_EDGE(c, ns, v)
    }
    float nn = normv[node];
    uint4 o;
    o.x = pack2(nn * acc0, nn * acc1);
    o.y = pack2(nn * acc2, nn * acc3);
    o.z = pack2(nn * acc4, nn * acc5);
    o.w = pack2(nn * acc6, nn * acc7);
    *((uint4*)(Hout + (size_t)node * RSTRIDE) + sub) = o;
}

// ------------------------------------------ fused hop2-SpMM + linear + ReLU (+gate)
// 4 lanes/node. Hop2 gathers Hah; A2h stays in regs. Linear: per-lane partials
// over the lane's 8 features of {h, Ah, A2h}, then 4-lane shfl_xor butterfly.
__global__ __launch_bounds__(256) void spmm_linear_kernel(
    const unsigned* __restrict__ Hh,     // h      (W block 0)
    const unsigned* __restrict__ Hah,    // Ah     (W block 1; gather source)
    const int* __restrict__ rowptr, const int* __restrict__ col,
    const float* __restrict__ normv,
    const float* __restrict__ W,         // [3*FDIM][FDIM] fp32
    const float* __restrict__ bias,      // [FDIM]
    unsigned* __restrict__ Hout,         // new h (in-place over Hh is safe: own row only)
    float* __restrict__ gatev, const float* __restrict__ w_gate,
    const float* __restrict__ b_gate, int do_gate, int N)
{
    int node = blockIdx.x * 64 + (threadIdx.x >> 2);
    int sub = threadIdx.x & 3;
    if (node >= N) return;
    int s = rowptr[node], e = rowptr[node + 1];
    float acc0 = 0.f, acc1 = 0.f, acc2 = 0.f, acc3 = 0.f;
    float acc4 = 0.f, acc5 = 0.f, acc6 = 0.f, acc7 = 0.f;
    int k = s;
    for (; k + 8 <= e; k += 8) {
        int c0 = col[k + 0], c1 = col[k + 1], c2 = col[k + 2], c3 = col[k + 3];
        int c4 = col[k + 4], c5 = col[k + 5], c6 = col[k + 6], c7 = col[k + 7];
        uint4 v0 = *((const uint4*)(Hah + (size_t)c0 * RSTRIDE) + sub);
        uint4 v1 = *((const uint4*)(Hah + (size_t)c1 * RSTRIDE) + sub);
        uint4 v2 = *((const uint4*)(Hah + (size_t)c2 * RSTRIDE) + sub);
        uint4 v3 = *((const uint4*)(Hah + (size_t)c3 * RSTRIDE) + sub);
        uint4 v4 = *((const uint4*)(Hah + (size_t)c4 * RSTRIDE) + sub);
        uint4 v5 = *((const uint4*)(Hah + (size_t)c5 * RSTRIDE) + sub);
        uint4 v6 = *((const uint4*)(Hah + (size_t)c6 * RSTRIDE) + sub);
        uint4 v7 = *((const uint4*)(Hah + (size_t)c7 * RSTRIDE) + sub);
        float n0 = normv[c0], n1 = normv[c1], n2 = normv[c2], n3 = normv[c3];
        float n4 = normv[c4], n5 = normv[c5], n6 = normv[c6], n7 = normv[c7];
        GATHER_EDGE(c0, n0, v0) GATHER_EDGE(c1, n1, v1)
        GATHER_EDGE(c2, n2, v2) GATHER_EDGE(c3, n3, v3)
        GATHER_EDGE(c4, n4, v4) GATHER_EDGE(c5, n5, v5)
        GATHER_EDGE(c6, n6, v6) GATHER_EDGE(c7, n7, v7)
    }
    for (; k < e; ++k) {
        int c = col[k];
        float ns = normv[c];
        uint4 v = *((const uint4*)(Hah + (size_t)c * RSTRIDE) + sub);
        GATHER_EDGE(c, ns, v)
    }
    float nn = normv[node];
    acc0 *= nn; acc1 *= nn; acc2 *= nn; acc3 *= nn;
    acc4 *= nn; acc5 *= nn; acc6 *= nn; acc7 *= nn;   // = A2h features sub*8..+7

    // own rows of h and Ah (coalesced 16 B/lane)
    uint4 va = *((const uint4*)(Hh  + (size_t)node * RSTRIDE) + sub);
    uint4 vb = *((const uint4*)(Hah + (size_t)node * RSTRIDE) + sub);
    float fa0 = bf_lo(va.x), fa1 = bf_hi(va.x), fa2 = bf_lo(va.y), fa3 = bf_hi(va.y);
    float fa4 = bf_lo(va.z), fa5 = bf_hi(va.z), fa6 = bf_lo(va.w), fa7 = bf_hi(va.w);
    float fb0 = bf_lo(vb.x), fb1 = bf_hi(vb.x), fb2 = bf_lo(vb.y), fb3 = bf_hi(vb.y);
    float fb4 = bf_lo(vb.z), fb5 = bf_hi(vb.z), fb6 = bf_lo(vb.w), fb7 = bf_hi(vb.w);

    float part[FDIM];
#pragma unroll
    for (int j = 0; j < FDIM; ++j) part[j] = 0.0f;

    auto mm = [&](int i, float xa, float xb, float xc) {
        int ig = sub * 8 + i;
        if (ig >= FDIM) return;             // pad feature: contributes nothing
        const float* w0 = W + (size_t)ig * FDIM;
        const float* w1 = W + (size_t)(FDIM + ig) * FDIM;
        const float* w2 = W + (size_t)(2 * FDIM + ig) * FDIM;
#pragma unroll
        for (int j = 0; j < FDIM; ++j)
            part[j] = fmaf(xa, w0[j], fmaf(xb, w1[j], fmaf(xc, w2[j], part[j])));
    };
    mm(0, fa0, fb0, acc0); mm(1, fa1, fb1, acc1);
    mm(2, fa2, fb2, acc2); mm(3, fa3, fb3, acc3);
    mm(4, fa4, fb4, acc4); mm(5, fa5, fb5, acc5);
    mm(6, fa6, fb6, acc6); mm(7, fa7, fb7, acc7);

    // butterfly over the 4-lane group (lanes 4k..4k+3)
#pragma unroll
    for (int j = 0; j < FDIM; ++j) part[j] += __shfl_xor(part[j], 1);
#pragma unroll
    for (int j = 0; j < FDIM; ++j) part[j] += __shfl_xor(part[j], 2);
#pragma unroll
    for (int j = 0; j < FDIM; ++j) part[j] = fmaxf(part[j] + bias[j], 0.0f);

    uint4 o;
    if (sub == 0)      { o.x = pack2(part[0],  part[1]);  o.y = pack2(part[2],  part[3]);
                         o.z = pack2(part[4],  part[5]);  o.w = pack2(part[6],  part[7]); }
    else if (sub == 1) { o.x = pack2(part[8],  part[9]);  o.y = pack2(part[10], part[11]);
                         o.z = pack2(part[12], part[13]); o.w = pack2(part[14], part[15]); }
    else if (sub == 2) { o.x = pack2(part[16], part[17]); o.y = pack2(part[18], part[19]);
                         o.z = pack2(part[20], part[21]); o.w = pack2(part[22], part[23]); }
    else               { o.x = pack2(part[24], part[25]); o.y = pack2(part[26], part[27]);
                         o.z = pack2(part[28], part[29]); o.w = pack2(part[30], 0.0f); }
    *((uint4*)(Hout + (size_t)node * RSTRIDE) + sub) = o;

    if (do_gate && sub == 0) {
        float g = b_gate[0];
#pragma unroll
        for (int j = 0; j < FDIM; ++j) g = fmaf(part[j], w_gate[j], g);
        gatev[node] = g;
    }
}

// ----------------------------------------------------------------- pooling

__global__ void soff_scan_kernel(const int* __restrict__ num, int* __restrict__ soff, int Bn) {
    if (threadIdx.x == 0 && blockIdx.x == 0) {
        int acc = 0;
        soff[0] = 0;
        for (int i = 0; i < Bn; ++i) { acc += num[i]; soff[i + 1] = acc; }
    }
}

__global__ __launch_bounds__(64) void graph_reduce_kernel(const float* __restrict__ gate,
                                                          const int* __restrict__ gid,
                                                          const int* __restrict__ soff, int Bn,
                                                          int Ntot,
                                                          float* __restrict__ gmax,
                                                          float* __restrict__ gden) {
    int g = blockIdx.x;
    if (g >= soff[Bn]) return;
    int s = lb_gid(gid, Ntot, g), e = lb_gid(gid, Ntot, g + 1);
    float m = -1e30f;
    for (int n = s + threadIdx.x; n < e; n += 64) m = fmaxf(m, gate[n]);
#pragma unroll
    for (int o = 32; o > 0; o >>= 1) m = fmaxf(m, __shfl_xor(m, o));
    float d = 0.0f;
    for (int n = s + threadIdx.x; n < e; n += 64) d += expf(gate[n] - m);
#pragma unroll
    for (int o = 32; o > 0; o >>= 1) d += __shfl_xor(d, o);
    if (threadIdx.x == 0) { gmax[g] = m; gden[g] = d; }
}

// One block per (sample, slot); writes zeros into pad slots (replaces d_out memset).
__global__ __launch_bounds__(64) void rep_scatter_kernel(const unsigned short* __restrict__ H,
                                                         const float* __restrict__ gate,
                                                         const int* __restrict__ gid,
                                                         const int* __restrict__ soff,
                                                         int MAXG, int Ntot,
                                                         const float* __restrict__ gmax,
                                                         const float* __restrict__ gden,
                                                         float* __restrict__ out) {
    int s = blockIdx.x / MAXG;
    int pos = blockIdx.x % MAXG;
    int t = threadIdx.x;
    if (t >= FDIM) return;
    int gbeg = soff[s], gend = soff[s + 1];
    float* op = out + ((size_t)s * MAXG + pos) * FDIM + t;
    if (pos >= gend - gbeg) { *op = 0.0f; return; }
    int g = gbeg + pos;
    int ns = lb_gid(gid, Ntot, g), ne = lb_gid(gid, Ntot, g + 1);
    float m = gmax[g], den = gden[g];
    float acc = 0.0f;
    for (int n = ns; n < ne; ++n) {
        float hv = __uint_as_float((unsigned)H[(size_t)n * FPAD + t] << 16);
        acc += expf(gate[n] - m) * hv;
    }
    *op = acc / den;
}

// ------------------------------------------------------------------ launcher

extern "C" void kernel_launch(void* const* d_in, const int* in_sizes, int n_in,
                              void* d_out, int out_size, void* d_ws, size_t ws_size,
                              hipStream_t stream) {
    const float* x      = (const float*)d_in[0];
    const float* Ws     = (const float*)d_in[1];
    const float* bs     = (const float*)d_in[2];
    const float* w_gate = (const float*)d_in[3];
    const float* b_gate = (const float*)d_in[4];
    const int* src       = (const int*)d_in[5];
    const int* dst       = (const int*)d_in[6];
    const int* graph_ids = (const int*)d_in[7];
    const int* num       = (const int*)d_in[8];
    float* out  = (float*)d_out;

    const int N  = in_sizes[7];
    const int E  = in_sizes[5];
    const int Bn = in_sizes[8];
    const int F  = in_sizes[3];            // 31
    const int L  = in_sizes[2] / F;        // 5
    const int nW = in_sizes[1];            // L * 3F * F
    const int WperL = nW / L;              // 3F*F
    const int MAXG = out_size / (Bn * F);  // 120
    const int Gmax = Bn * MAXG;

    const int nbuk = (N + CW - 1) / CW;    // 196 for N=400K
    const int cap  = E / nbuk + E / (8 * nbuk) + 2048;

    // ---- workspace carve-up
    char* p = (char*)d_ws;
    auto alloc = [&](size_t bytes) {
        void* r = (void*)p;
        p += (bytes + 255) & ~(size_t)255;
        return r;
    };
    unsigned* HA = (unsigned*)alloc((size_t)N * RSTRIDE * 4);   // packed bf16 rows
    unsigned* HB = (unsigned*)alloc((size_t)N * RSTRIDE * 4);
    int*   colw  = (int*)alloc((size_t)E * 4);
    int*   bkt   = (int*)alloc((size_t)nbuk * cap * 4);
    int*   gcnt  = (int*)alloc((size_t)nbuk * 4);
    int*   deg   = (int*)alloc((size_t)N * 4);
    int*   rowp  = (int*)alloc((size_t)(N + 1) * 4);
    float* normv = (float*)alloc((size_t)N * 4);
    float* gatev = (float*)alloc((size_t)N * 4);
    float* gmax  = (float*)alloc((size_t)Gmax * 4);
    float* gden  = (float*)alloc((size_t)Gmax * 4);
    int*   soff  = (int*)alloc((size_t)(Bn + 1) * 4);
    const int NB = (N + 255) / 256;
    int*   parts = (int*)alloc((size_t)NB * 4);

    // ---- zero init (only gcnt needs it now)
    (void)hipMemsetAsync(gcnt, 0, (size_t)nbuk * 4, stream);

    // ---- CSR build via LDS-staged multisplit
    const int NT = (E + TILE - 1) / TILE;
    multisplit_kernel<<<NT, 256, 0, stream>>>(src, dst, gcnt, bkt, cap, E, nbuk);
    bucket_deg_kernel<<<nbuk, 1024, 0, stream>>>(bkt, gcnt, deg, cap, N);
    scan_block_kernel<<<NB, 256, 0, stream>>>(deg, rowp, parts, N);
    scan_partials_kernel<<<1, 256, 0, stream>>>(parts, NB);
    finalize_kernel<<<NB, 256, 0, stream>>>(rowp, parts, deg, normv, N, E);
    bucket_fill_kernel<<<nbuk, 1024, 0, stream>>>(bkt, gcnt, rowp, colw, cap, N);

    // ---- input layout (fp32 -> packed bf16, pad 31 -> 32)
    cast_x_kernel<<<(N * RSTRIDE + 255) / 256, 256, 0, stream>>>(x, HA, N);

    // ---- 5 TAGConv layers: hop1 (spmm) then fused hop2+linear(+gate)
    const int SB = (N + 63) / 64;
    for (int l = 0; l < L; ++l) {
        spmm_kernel<<<SB, 256, 0, stream>>>(HA, HB, rowp, colw, normv, N);
        spmm_linear_kernel<<<SB, 256, 0, stream>>>(HA, HB, rowp, colw, normv,
                                                   Ws + (size_t)l * WperL,
                                                   bs + (size_t)l * F,
                                                   HA, gatev, w_gate, b_gate,
                                                   (l == L - 1) ? 1 : 0, N);
    }

    // ---- gated attention pooling + padded scatter (binary-search bounds)
    soff_scan_kernel<<<1, 64, 0, stream>>>(num, soff, Bn);
    graph_reduce_kernel<<<Gmax, 64, 0, stream>>>(gatev, graph_ids, soff, Bn, N, gmax, gden);
    rep_scatter_kernel<<<Gmax, 64, 0, stream>>>((const unsigned short*)HA, gatev, graph_ids,
                                                soff, MAXG, N, gmax, gden, out);
    (void)n_in; (void)ws_size;
}

// Round 9
// 1968.493 us; speedup vs baseline: 1.4768x; 1.4768x over previous
//
#include <hip/hip_runtime.h>
#include <hip/hip_bf16.h>

// Problem constants (F is hard-coded 31 in the reference / TAG)
#define FDIM 31
#define FPAD 32      // padded row length in elements
#define RSTRIDE 16   // row stride in uints (32 bf16 = 64 B = 16 uints = 1 cache line)

// Coarse bucketing for CSR build: 2048 nodes per bucket
#define CBITS 11
#define CW    (1 << CBITS)
#define MAXBUK 256
#define TILE 4096

// ---- bf16 pack/unpack helpers (packed as 2 bf16 per uint, little-endian)
__device__ __forceinline__ float bf_lo(unsigned u) { return __uint_as_float(u << 16); }
__device__ __forceinline__ float bf_hi(unsigned u) { return __uint_as_float(u & 0xFFFF0000u); }
__device__ __forceinline__ unsigned pack2(float lo, float hi) {
    unsigned a = __float_as_uint(lo), b = __float_as_uint(hi);
    unsigned ra = (a + 0x7FFFu + ((a >> 16) & 1u)) >> 16;   // RNE
    unsigned rb = (b + 0x7FFFu + ((b >> 16) & 1u)) >> 16;
    return ra | (rb << 16);
}

// first index in sorted gid[0..Ntot) with gid[idx] >= g
__device__ __forceinline__ int lb_gid(const int* __restrict__ gid, int Ntot, int g) {
    int lo = 0, hi = Ntot;
    while (lo < hi) { int mid = (lo + hi) >> 1; if (gid[mid] < g) lo = mid + 1; else hi = mid; }
    return lo;
}

// --------------------------------------------------- multisplit (level 1)
__global__ __launch_bounds__(256) void multisplit_kernel(
    const int* __restrict__ src, const int* __restrict__ dst,
    int* __restrict__ gcnt, int* __restrict__ bucketed,
    int cap, int E, int nbuk)
{
    __shared__ int ordered[TILE];
    __shared__ int hist[MAXBUK];
    __shared__ int lofs[MAXBUK + 1];
    __shared__ int base_[MAXBUK];
    __shared__ int cur[MAXBUK];
    const int tid = threadIdx.x;
    const int e0 = blockIdx.x * TILE;
    const int n = min(TILE, E - e0);
    if (tid < MAXBUK) hist[tid] = 0;
    __syncthreads();
    for (int i = tid; i < n; i += 256)
        atomicAdd(&hist[dst[e0 + i] >> CBITS], 1);
    __syncthreads();
    if (tid == 0) {
        int a = 0;
        for (int b = 0; b < nbuk; ++b) { lofs[b] = a; a += hist[b]; }
        lofs[nbuk] = a;
    }
    __syncthreads();
    if (tid < nbuk) {
        int h = hist[tid];
        base_[tid] = h ? atomicAdd(&gcnt[tid], h) : 0;
        cur[tid] = lofs[tid];
    }
    __syncthreads();
    for (int i = tid; i < n; i += 256) {
        int s = src[e0 + i], d = dst[e0 + i];
        int b = d >> CBITS;
        int r = atomicAdd(&cur[b], 1);
        ordered[r] = (s << CBITS) | (d & (CW - 1));
    }
    __syncthreads();
    for (int i = tid; i < n; i += 256) {
        int lo = 0, hi = nbuk;
        while (hi - lo > 1) {
            int mid = (lo + hi) >> 1;
            if (lofs[mid] <= i) lo = mid; else hi = mid;
        }
        int b = lo;
        int pos = base_[b] + (i - lofs[b]);
        if (pos < cap) bucketed[(size_t)b * cap + pos] = ordered[i];
    }
}

// ---------------------------------- tiny serial scans: gcnt->bbase, num->soff
__global__ void small_scans_kernel(const int* __restrict__ num, int* __restrict__ soff, int Bn,
                                   const int* __restrict__ gcnt, int* __restrict__ bbase,
                                   int nbuk, int cap) {
    if (threadIdx.x == 0 && blockIdx.x == 0) {
        int acc = 0; soff[0] = 0;
        for (int i = 0; i < Bn; ++i) { acc += num[i]; soff[i + 1] = acc; }
        int a = 0;
        for (int b = 0; b < nbuk; ++b) { bbase[b] = a; a += min(gcnt[b], cap); }
    }
}

// -------------------- per-bucket: hist + LDS scan + rowptr/normv + CSR fill
__global__ __launch_bounds__(1024) void bucket_build_kernel(
    const int* __restrict__ bucketed, const int* __restrict__ gcnt,
    const int* __restrict__ bbase,
    int* __restrict__ rowptr, float* __restrict__ normv, int* __restrict__ col,
    int cap, int N, int E, int nbuk)
{
    __shared__ int hist[CW];   // counts, then inclusive scan
    __shared__ int lcur[CW];   // fill cursors
    const int b = blockIdx.x, tid = threadIdx.x;
    hist[tid] = 0; hist[tid + 1024] = 0;
    __syncthreads();
    const int cnt = min(gcnt[b], cap);
    const int* reg = bucketed + (size_t)b * cap;
    for (int i = tid; i < cnt; i += 1024)
        atomicAdd(&hist[reg[i] & (CW - 1)], 1);
    __syncthreads();
    int c0 = hist[tid], c1 = hist[tid + 1024];   // own pre-scan counts
    // Hillis-Steele inclusive scan over 2048 entries with 1024 threads
    for (int off = 1; off < CW; off <<= 1) {
        int a0 = (tid >= off) ? hist[tid - off] : 0;
        int a1 = (tid + 1024 >= off) ? hist[tid + 1024 - off] : 0;
        __syncthreads();
        hist[tid] += a0; hist[tid + 1024] += a1;
        __syncthreads();
    }
    const int base = bbase[b];
    const int base_node = b << CBITS;
    int node = base_node + tid;
    if (node < N) {
        int r = base + hist[tid] - c0;           // exclusive
        rowptr[node] = r; lcur[tid] = r;
        normv[node] = rsqrtf((float)(c0 > 0 ? c0 : 1));
    }
    node = base_node + tid + 1024;
    if (node < N) {
        int r = base + hist[tid + 1024] - c1;
        rowptr[node] = r; lcur[tid + 1024] = r;
        normv[node] = rsqrtf((float)(c1 > 0 ? c1 : 1));
    }
    if (b == nbuk - 1 && tid == 0) rowptr[N] = E;
    __syncthreads();
    for (int i = tid; i < cnt; i += 1024) {
        int e = reg[i];
        int p = atomicAdd(&lcur[e & (CW - 1)], 1);
        col[p] = e >> CBITS;
    }
}

// ---- fp32 x -> packed bf16 padded rows (one thread per packed uint)
__global__ void cast_x_kernel(const float* __restrict__ x, unsigned* __restrict__ A, int N) {
    int idx = blockIdx.x * 256 + threadIdx.x;
    if (idx >= N * RSTRIDE) return;
    int n = idx >> 4, q = idx & 15;
    int f0 = 2 * q, f1 = 2 * q + 1;
    float lo = (f0 < FDIM) ? x[(size_t)n * FDIM + f0] : 0.0f;
    float hi = (f1 < FDIM) ? x[(size_t)n * FDIM + f1] : 0.0f;
    A[idx] = pack2(lo, hi);
}

// ---- shared gather body: accumulate norm-scaled neighbor rows into acc[8]
#define GATHER_EDGE(nN, vN)                                                            \
    acc0 = fmaf(nN, bf_lo(vN.x), acc0); acc1 = fmaf(nN, bf_hi(vN.x), acc1);            \
    acc2 = fmaf(nN, bf_lo(vN.y), acc2); acc3 = fmaf(nN, bf_hi(vN.y), acc3);            \
    acc4 = fmaf(nN, bf_lo(vN.z), acc4); acc5 = fmaf(nN, bf_hi(vN.z), acc5);            \
    acc6 = fmaf(nN, bf_lo(vN.w), acc6); acc7 = fmaf(nN, bf_hi(vN.w), acc7);

// ------------------------------------------------------------------ SpMM hop
// bf16 rows: 64 B/row = 1 line. 4 lanes/node, 16 B (uint4) each. Edge loop
// unrolled x8 for MLP. KEEP THIS KERNEL LEAN: occupancy directly scales the
// random-gather bandwidth (R8 post-mortem: VGPR 120 -> 22% occ -> 1/2.7 BW).
__global__ __launch_bounds__(256) void spmm_kernel(const unsigned* __restrict__ Hin,
                                                   unsigned* __restrict__ Hout,
                                                   const int* __restrict__ rowptr,
                                                   const int* __restrict__ col,
                                                   const float* __restrict__ normv, int N) {
    int node = blockIdx.x * 64 + (threadIdx.x >> 2);
    int sub = threadIdx.x & 3;
    if (node >= N) return;
    int s = rowptr[node], e = rowptr[node + 1];
    float acc0 = 0.f, acc1 = 0.f, acc2 = 0.f, acc3 = 0.f;
    float acc4 = 0.f, acc5 = 0.f, acc6 = 0.f, acc7 = 0.f;
    int k = s;
    for (; k + 8 <= e; k += 8) {
        int c0 = col[k + 0], c1 = col[k + 1], c2 = col[k + 2], c3 = col[k + 3];
        int c4 = col[k + 4], c5 = col[k + 5], c6 = col[k + 6], c7 = col[k + 7];
        uint4 v0 = *((const uint4*)(Hin + (size_t)c0 * RSTRIDE) + sub);
        uint4 v1 = *((const uint4*)(Hin + (size_t)c1 * RSTRIDE) + sub);
        uint4 v2 = *((const uint4*)(Hin + (size_t)c2 * RSTRIDE) + sub);
        uint4 v3 = *((const uint4*)(Hin + (size_t)c3 * RSTRIDE) + sub);
        uint4 v4 = *((const uint4*)(Hin + (size_t)c4 * RSTRIDE) + sub);
        uint4 v5 = *((const uint4*)(Hin + (size_t)c5 * RSTRIDE) + sub);
        uint4 v6 = *((const uint4*)(Hin + (size_t)c6 * RSTRIDE) + sub);
        uint4 v7 = *((const uint4*)(Hin + (size_t)c7 * RSTRIDE) + sub);
        float n0 = normv[c0], n1 = normv[c1], n2 = normv[c2], n3 = normv[c3];
        float n4 = normv[c4], n5 = normv[c5], n6 = normv[c6], n7 = normv[c7];
        GATHER_EDGE(n0, v0) GATHER_EDGE(n1, v1) GATHER_EDGE(n2, v2) GATHER_EDGE(n3, v3)
        GATHER_EDGE(n4, v4) GATHER_EDGE(n5, v5) GATHER_EDGE(n6, v6) GATHER_EDGE(n7, v7)
    }
    for (; k < e; ++k) {
        int c = col[k];
        float ns = normv[c];
        uint4 v = *((const uint4*)(Hin + (size_t)c * RSTRIDE) + sub);
        GATHER_EDGE(ns, v)
    }
    float nn = normv[node];
    uint4 o;
    o.x = pack2(nn * acc0, nn * acc1);
    o.y = pack2(nn * acc2, nn * acc3);
    o.z = pack2(nn * acc4, nn * acc5);
    o.w = pack2(nn * acc6, nn * acc7);
    *((uint4*)(Hout + (size_t)node * RSTRIDE) + sub) = o;
}

// --------------------------- fused linear + relu (+gate on last layer)
// Thread-per-node; W indexed by compile-time constants -> lane-uniform scalar
// loads (no VGPR blowup — the R8 mistake was lane-dependent W indexing).
__global__ __launch_bounds__(256) void linear_relu_kernel(const unsigned* __restrict__ A,
                                                          const unsigned* __restrict__ Bh,
                                                          const unsigned* __restrict__ Ch,
                                                          const float* __restrict__ W,
                                                          const float* __restrict__ bias,
                                                          unsigned* __restrict__ out_h,
                                                          float* __restrict__ gatev,
                                                          const float* __restrict__ w_gate,
                                                          const float* __restrict__ b_gate,
                                                          int do_gate, int N) {
    int n = blockIdx.x * 256 + threadIdx.x;
    if (n >= N) return;
    float out[FDIM];
#pragma unroll
    for (int j = 0; j < FDIM; ++j) out[j] = bias[j];
#pragma unroll 1
    for (int blk = 0; blk < 3; ++blk) {
        const unsigned* bp = (blk == 0) ? A : ((blk == 1) ? Bh : Ch);
        const uint4* r4p = (const uint4*)(bp + (size_t)n * RSTRIDE);
        uint4 r4[4];
#pragma unroll
        for (int q = 0; q < 4; ++q) r4[q] = r4p[q];
        const unsigned* ru = (const unsigned*)r4;
        float rr[FPAD];
#pragma unroll
        for (int q = 0; q < RSTRIDE; ++q) { rr[2 * q] = bf_lo(ru[q]); rr[2 * q + 1] = bf_hi(ru[q]); }
        const float* Wb = W + blk * FDIM * FDIM;
#pragma unroll
        for (int i = 0; i < FDIM; ++i) {
            float v = rr[i];
#pragma unroll
            for (int j = 0; j < FDIM; ++j) out[j] = fmaf(v, Wb[i * FDIM + j], out[j]);
        }
    }
#pragma unroll
    for (int j = 0; j < FDIM; ++j) out[j] = fmaxf(out[j], 0.0f);
    unsigned* o = out_h + (size_t)n * RSTRIDE;
    uint4 w0, w1, w2, w3;
    w0.x = pack2(out[0], out[1]);   w0.y = pack2(out[2], out[3]);
    w0.z = pack2(out[4], out[5]);   w0.w = pack2(out[6], out[7]);
    w1.x = pack2(out[8], out[9]);   w1.y = pack2(out[10], out[11]);
    w1.z = pack2(out[12], out[13]); w1.w = pack2(out[14], out[15]);
    w2.x = pack2(out[16], out[17]); w2.y = pack2(out[18], out[19]);
    w2.z = pack2(out[20], out[21]); w2.w = pack2(out[22], out[23]);
    w3.x = pack2(out[24], out[25]); w3.y = pack2(out[26], out[27]);
    w3.z = pack2(out[28], out[29]); w3.w = pack2(out[30], 0.0f);
    ((uint4*)o)[0] = w0; ((uint4*)o)[1] = w1; ((uint4*)o)[2] = w2; ((uint4*)o)[3] = w3;
    if (do_gate) {
        float g = b_gate[0];
#pragma unroll
        for (int j = 0; j < FDIM; ++j) g = fmaf(out[j], w_gate[j], g);
        gatev[n] = g;
    }
}

// ----------------------------------------------------------------- pooling

__global__ __launch_bounds__(64) void graph_reduce_kernel(const float* __restrict__ gate,
                                                          const int* __restrict__ gid,
                                                          const int* __restrict__ soff, int Bn,
                                                          int Ntot,
                                                          float* __restrict__ gmax,
                                                          float* __restrict__ gden) {
    int g = blockIdx.x;
    if (g >= soff[Bn]) return;
    int s = lb_gid(gid, Ntot, g), e = lb_gid(gid, Ntot, g + 1);
    float m = -1e30f;
    for (int n = s + threadIdx.x; n < e; n += 64) m = fmaxf(m, gate[n]);
#pragma unroll
    for (int o = 32; o > 0; o >>= 1) m = fmaxf(m, __shfl_xor(m, o));
    float d = 0.0f;
    for (int n = s + threadIdx.x; n < e; n += 64) d += expf(gate[n] - m);
#pragma unroll
    for (int o = 32; o > 0; o >>= 1) d += __shfl_xor(d, o);
    if (threadIdx.x == 0) { gmax[g] = m; gden[g] = d; }
}

// One block per (sample, slot); writes zeros into pad slots (replaces d_out memset).
__global__ __launch_bounds__(64) void rep_scatter_kernel(const unsigned short* __restrict__ H,
                                                         const float* __restrict__ gate,
                                                         const int* __restrict__ gid,
                                                         const int* __restrict__ soff,
                                                         int MAXG, int Ntot,
                                                         const float* __restrict__ gmax,
                                                         const float* __restrict__ gden,
                                                         float* __restrict__ out) {
    int s = blockIdx.x / MAXG;
    int pos = blockIdx.x % MAXG;
    int t = threadIdx.x;
    if (t >= FDIM) return;
    int gbeg = soff[s], gend = soff[s + 1];
    float* op = out + ((size_t)s * MAXG + pos) * FDIM + t;
    if (pos >= gend - gbeg) { *op = 0.0f; return; }
    int g = gbeg + pos;
    int ns = lb_gid(gid, Ntot, g), ne = lb_gid(gid, Ntot, g + 1);
    float m = gmax[g], den = gden[g];
    float acc = 0.0f;
    for (int n = ns; n < ne; ++n) {
        float hv = __uint_as_float((unsigned)H[(size_t)n * FPAD + t] << 16);
        acc += expf(gate[n] - m) * hv;
    }
    *op = acc / den;
}

// ------------------------------------------------------------------ launcher

extern "C" void kernel_launch(void* const* d_in, const int* in_sizes, int n_in,
                              void* d_out, int out_size, void* d_ws, size_t ws_size,
                              hipStream_t stream) {
    const float* x      = (const float*)d_in[0];
    const float* Ws     = (const float*)d_in[1];
    const float* bs     = (const float*)d_in[2];
    const float* w_gate = (const float*)d_in[3];
    const float* b_gate = (const float*)d_in[4];
    const int* src       = (const int*)d_in[5];
    const int* dst       = (const int*)d_in[6];
    const int* graph_ids = (const int*)d_in[7];
    const int* num       = (const int*)d_in[8];
    float* out  = (float*)d_out;

    const int N  = in_sizes[7];
    const int E  = in_sizes[5];
    const int Bn = in_sizes[8];
    const int F  = in_sizes[3];            // 31
    const int L  = in_sizes[2] / F;        // 5
    const int nW = in_sizes[1];            // L * 3F * F
    const int WperL = nW / L;              // 3F*F
    const int MAXG = out_size / (Bn * F);  // 120
    const int Gmax = Bn * MAXG;

    const int nbuk = (N + CW - 1) / CW;    // 196 for N=400K
    const int cap  = E / nbuk + E / (8 * nbuk) + 2048;

    // ---- workspace carve-up
    char* p = (char*)d_ws;
    auto alloc = [&](size_t bytes) {
        void* r = (void*)p;
        p += (bytes + 255) & ~(size_t)255;
        return r;
    };
    unsigned* HA = (unsigned*)alloc((size_t)N * RSTRIDE * 4);   // packed bf16 rows
    unsigned* HB = (unsigned*)alloc((size_t)N * RSTRIDE * 4);
    unsigned* HC = (unsigned*)alloc((size_t)N * RSTRIDE * 4);
    int*   colw  = (int*)alloc((size_t)E * 4);
    int*   bkt   = (int*)alloc((size_t)nbuk * cap * 4);
    int*   gcnt  = (int*)alloc((size_t)nbuk * 4);
    int*   bbase = (int*)alloc((size_t)nbuk * 4);
    int*   rowp  = (int*)alloc((size_t)(N + 1) * 4);
    float* normv = (float*)alloc((size_t)N * 4);
    float* gatev = (float*)alloc((size_t)N * 4);
    float* gmax  = (float*)alloc((size_t)Gmax * 4);
    float* gden  = (float*)alloc((size_t)Gmax * 4);
    int*   soff  = (int*)alloc((size_t)(Bn + 1) * 4);

    // ---- zero init (only gcnt)
    (void)hipMemsetAsync(gcnt, 0, (size_t)nbuk * 4, stream);

    // ---- CSR build: multisplit -> tiny scans -> per-bucket build (3 kernels)
    const int NT = (E + TILE - 1) / TILE;
    multisplit_kernel<<<NT, 256, 0, stream>>>(src, dst, gcnt, bkt, cap, E, nbuk);
    small_scans_kernel<<<1, 64, 0, stream>>>(num, soff, Bn, gcnt, bbase, nbuk, cap);
    bucket_build_kernel<<<nbuk, 1024, 0, stream>>>(bkt, gcnt, bbase, rowp, normv, colw,
                                                   cap, N, E, nbuk);

    // ---- input layout (fp32 -> packed bf16, pad 31 -> 32)
    cast_x_kernel<<<(N * RSTRIDE + 255) / 256, 256, 0, stream>>>(x, HA, N);

    // ---- 5 TAGConv layers
    const int SB = (N + 63) / 64;
    const int NB = (N + 255) / 256;
    for (int l = 0; l < L; ++l) {
        spmm_kernel<<<SB, 256, 0, stream>>>(HA, HB, rowp, colw, normv, N);
        spmm_kernel<<<SB, 256, 0, stream>>>(HB, HC, rowp, colw, normv, N);
        linear_relu_kernel<<<NB, 256, 0, stream>>>(HA, HB, HC, Ws + (size_t)l * WperL,
                                                   bs + (size_t)l * F, HA,
                                                   gatev, w_gate, b_gate,
                                                   (l == L - 1) ? 1 : 0, N);
    }

    // ---- gated attention pooling + padded scatter (binary-search bounds)
    graph_reduce_kernel<<<Gmax, 64, 0, stream>>>(gatev, graph_ids, soff, Bn, N, gmax, gden);
    rep_scatter_kernel<<<Gmax, 64, 0, stream>>>((const unsigned short*)HA, gatev, graph_ids,
                                                soff, MAXG, N, gmax, gden, out);
    (void)n_in; (void)ws_size;
}